// Round 5
// baseline (2682.642 us; speedup 1.0000x reference)
//
#include <hip/hip_runtime.h>

#define N_PTS   16384
#define NPOINT  1024
#define NSAMPLE 64
#define R2 ((float)(0.3 * 0.3))

typedef float v2f __attribute__((ext_vector_type(2)));

#define FPS_T  512
#define PPT    (N_PTS / FPS_T)   // 32 points per thread
#define NPAIR  (PPT / 2)         // 16 float2 pairs
#define NWAVE  (FPS_T / 64)      // 8 waves

// ---------------------------------------------------------------------------
// Kernel 1: furthest point sampling. One block per batch, 512 threads,
// 32 points/thread in registers as float2 pairs (v_pk_* math).
// ONE barrier per iteration: value-only wave argmax; the winning lane
// (ballot+ctz; exact because fmax is a selection) recovers its point's
// coordinates from registers and publishes (val,x,y,z) as a float4;
// after the barrier every thread redundantly reduces the 8 wave entries.
// Double-buffered by i&1 so no second barrier is needed.
// ---------------------------------------------------------------------------
__global__ __launch_bounds__(FPS_T, 2) void fps_kernel(
    const float* __restrict__ xyz, float* __restrict__ out_newxyz) {
    const int b = blockIdx.x;
    const int t = threadIdx.x;
    const int wave = t >> 6;
    const int lane = t & 63;
    const float* __restrict__ X = xyz + (size_t)b * N_PTS * 3;

    v2f px[NPAIR], py[NPAIR], pz[NPAIR], md[NPAIR];
#pragma unroll
    for (int j = 0; j < NPAIR; ++j) {
        int nA = (2 * j) * FPS_T + t;       // pair covers rows 2j and 2j+1
        int nB = (2 * j + 1) * FPS_T + t;
        px[j].x = X[3 * nA];     px[j].y = X[3 * nB];
        py[j].x = X[3 * nA + 1]; py[j].y = X[3 * nB + 1];
        pz[j].x = X[3 * nA + 2]; pz[j].y = X[3 * nB + 2];
        md[j].x = 1e10f;         md[j].y = 1e10f;
    }

    __shared__ __align__(16) float4 s_best[2][NWAVE];

    float lx = X[0], ly = X[1], lz = X[2];
    if (t == 0) {
        out_newxyz[b * NPOINT * 3 + 0] = lx;
        out_newxyz[b * NPOINT * 3 + 1] = ly;
        out_newxyz[b * NPOINT * 3 + 2] = lz;
    }

    for (int i = 1; i < NPOINT; ++i) {
        v2f lx2, ly2, lz2;
        lx2.x = lx; lx2.y = lx;
        ly2.x = ly; ly2.y = ly;
        lz2.x = lz; lz2.y = lz;
        v2f tv2;
        tv2.x = -1.0f; tv2.y = -1.0f;
        // --- update mindist (packed), track per-thread max value only ---
#pragma unroll
        for (int j = 0; j < NPAIR; ++j) {
            v2f dx = px[j] - lx2, dy = py[j] - ly2, dz = pz[j] - lz2;
            v2f d = dx * dx + dy * dy + dz * dz;   // same expr tree as passing kernel
            v2f m;
            m.x = fminf(md[j].x, d.x);
            m.y = fminf(md[j].y, d.y);
            md[j] = m;
            tv2.x = fmaxf(tv2.x, m.x);
            tv2.y = fmaxf(tv2.y, m.y);
        }
        float tv = fmaxf(tv2.x, tv2.y);
        // --- wave max (value only) ---
        float wv = tv;
#pragma unroll
        for (int off = 32; off > 0; off >>= 1)
            wv = fmaxf(wv, __shfl_xor(wv, off, 64));
        // --- first lane holding the max publishes value + ITS coords ---
        unsigned long long mask = __ballot(tv == wv);
        if (lane == (int)__builtin_ctzll(mask)) {
            float bx = 0.f, by = 0.f, bz = 0.f;
#pragma unroll
            for (int j = NPAIR - 1; j >= 0; --j) {
                // descending global point order (.y = row 2j+1 before .x = row 2j)
                if (md[j].y == wv) { bx = px[j].y; by = py[j].y; bz = pz[j].y; }
                if (md[j].x == wv) { bx = px[j].x; by = py[j].x; bz = pz[j].x; }
            }
            s_best[i & 1][wave] = make_float4(wv, bx, by, bz);
        }
        __syncthreads();
        // --- all threads redundantly reduce the 8 wave winners ---
        float4 best = s_best[i & 1][0];
#pragma unroll
        for (int k = 1; k < NWAVE; ++k) {
            float4 c = s_best[i & 1][k];
            if (c.x > best.x) best = c;   // strict >: first wave wins ties
        }
        lx = best.y; ly = best.z; lz = best.w;
        if (t == 0) {
            float* o = out_newxyz + b * NPOINT * 3 + 3 * i;
            o[0] = lx; o[1] = ly; o[2] = lz;
        }
    }
}

// ---------------------------------------------------------------------------
// Kernel 2: fused ball query + grouping + 3-layer MLP + max over samples.
// Unchanged from R3 (passed; ~350 us timed).
// ---------------------------------------------------------------------------
__global__ __launch_bounds__(256, 2) void bq_mlp_kernel(
    const float* __restrict__ xyz, const float* __restrict__ feat,
    const float* __restrict__ W1, const float* __restrict__ b1,
    const float* __restrict__ W2, const float* __restrict__ b2,
    const float* __restrict__ W3, const float* __restrict__ b3,
    const float* __restrict__ newxyz, float* __restrict__ out) {
    const int wave = threadIdx.x >> 6;
    const int lane = threadIdx.x & 63;
    const int q = blockIdx.x * 4 + wave;   // 0..4095
    const int b = q >> 10;
    const int p = q & 1023;
    const float* __restrict__ X = xyz  + (size_t)b * N_PTS * 3;
    const float* __restrict__ F = feat + (size_t)b * N_PTS * 3;

    const float cx = newxyz[3 * q], cy = newxyz[3 * q + 1], cz = newxyz[3 * q + 2];

    __shared__ __align__(16) float g[4][NSAMPLE][8];
    __shared__ __align__(16) float h[4][NSAMPLE][64];

    float w1r[6];
#pragma unroll
    for (int k = 0; k < 6; ++k) w1r[k] = W1[lane * 6 + k];
    const float b1r = b1[lane];
    const float b2r = b2[lane];

    // --- ball query: first NSAMPLE points (index order) with d2 < R2 ---
    int count = 0;
    for (int base = 0; base < N_PTS; base += 64) {
        int n = base + lane;
        float x = X[3 * n], y = X[3 * n + 1], z = X[3 * n + 2];
        float dx = x - cx, dy = y - cy, dz = z - cz;
        float d2 = dx * dx + dy * dy + dz * dz;
        bool in = d2 < R2;
        unsigned long long mask = __ballot(in);
        int slot = count + __popcll(mask & ((1ull << lane) - 1ull));
        if (in && slot < NSAMPLE) {
            g[wave][slot][0] = dx; g[wave][slot][1] = dy; g[wave][slot][2] = dz;
            g[wave][slot][3] = F[3 * n]; g[wave][slot][4] = F[3 * n + 1];
            g[wave][slot][5] = F[3 * n + 2];
        }
        count += __popcll(mask);
        if (count >= NSAMPLE) break;
    }
    asm volatile("s_waitcnt lgkmcnt(0)" ::: "memory");
    if (count == 0) {
        float x = X[0], y = X[1], z = X[2];
        g[wave][lane][0] = x - cx; g[wave][lane][1] = y - cy; g[wave][lane][2] = z - cz;
        g[wave][lane][3] = F[0];   g[wave][lane][4] = F[1];   g[wave][lane][5] = F[2];
    } else if (lane >= count) {
        float v0 = g[wave][0][0], v1 = g[wave][0][1], v2 = g[wave][0][2];
        float v3 = g[wave][0][3], v4 = g[wave][0][4], v5 = g[wave][0][5];
        g[wave][lane][0] = v0; g[wave][lane][1] = v1; g[wave][lane][2] = v2;
        g[wave][lane][3] = v3; g[wave][lane][4] = v4; g[wave][lane][5] = v5;
    }
    __syncthreads();

    // --- phase A: layer 1 (6 -> 64), lane = output channel ---
    for (int s = 0; s < NSAMPLE; ++s) {
        const float4* g4 = reinterpret_cast<const float4*>(&g[wave][s][0]);
        float4 ga = g4[0], gb = g4[1];
        float a = fmaf(w1r[0], ga.x, b1r);
        a = fmaf(w1r[1], ga.y, a);
        a = fmaf(w1r[2], ga.z, a);
        a = fmaf(w1r[3], ga.w, a);
        a = fmaf(w1r[4], gb.x, a);
        a = fmaf(w1r[5], gb.y, a);
        h[wave][s][lane] = fmaxf(a, 0.0f);
    }
    __syncthreads();

    // --- load W2 row (64 regs) ---
    float w2r[64];
    {
        const float4* w4 = reinterpret_cast<const float4*>(W2 + (size_t)lane * 64);
#pragma unroll
        for (int cc = 0; cc < 16; ++cc) *reinterpret_cast<float4*>(&w2r[4 * cc]) = w4[cc];
    }

    // --- phase B: layer 2 (64 -> 64), in-place overwrite ---
#pragma unroll 2
    for (int s = 0; s < NSAMPLE; ++s) {
        float a0 = 0.f, a1 = 0.f, a2 = 0.f, a3 = 0.f;
        const float4* h4 = reinterpret_cast<const float4*>(&h[wave][s][0]);
#pragma unroll
        for (int cc = 0; cc < 16; ++cc) {
            float4 hv = h4[cc];
            a0 = fmaf(w2r[4 * cc + 0], hv.x, a0);
            a1 = fmaf(w2r[4 * cc + 1], hv.y, a1);
            a2 = fmaf(w2r[4 * cc + 2], hv.z, a2);
            a3 = fmaf(w2r[4 * cc + 3], hv.w, a3);
        }
        float v = fmaxf(b2r + ((a0 + a1) + (a2 + a3)), 0.0f);
        h[wave][s][lane] = v;   // same-wave in-order DS: safe after reads
    }
    __syncthreads();

    // --- load W3 rows lane and lane+64 ---
    float w3a[64], w3b[64];
    {
        const float4* wa = reinterpret_cast<const float4*>(W3 + (size_t)lane * 64);
        const float4* wb = reinterpret_cast<const float4*>(W3 + (size_t)(lane + 64) * 64);
#pragma unroll
        for (int cc = 0; cc < 16; ++cc) {
            *reinterpret_cast<float4*>(&w3a[4 * cc]) = wa[cc];
            *reinterpret_cast<float4*>(&w3b[4 * cc]) = wb[cc];
        }
    }
    const float b3r0 = b3[lane];
    const float b3r1 = b3[lane + 64];

    // --- phase C: layer 3 (64 -> 128) + max over samples ---
    float m0 = 0.0f, m1 = 0.0f;
#pragma unroll 2
    for (int s = 0; s < NSAMPLE; ++s) {
        float a0 = 0.f, a1 = 0.f, a2 = 0.f, a3 = 0.f;
        float c0 = 0.f, c1 = 0.f, c2 = 0.f, c3 = 0.f;
        const float4* h4 = reinterpret_cast<const float4*>(&h[wave][s][0]);
#pragma unroll
        for (int cc = 0; cc < 16; ++cc) {
            float4 hv = h4[cc];
            a0 = fmaf(w3a[4 * cc + 0], hv.x, a0);
            a1 = fmaf(w3a[4 * cc + 1], hv.y, a1);
            a2 = fmaf(w3a[4 * cc + 2], hv.z, a2);
            a3 = fmaf(w3a[4 * cc + 3], hv.w, a3);
            c0 = fmaf(w3b[4 * cc + 0], hv.x, c0);
            c1 = fmaf(w3b[4 * cc + 1], hv.y, c1);
            c2 = fmaf(w3b[4 * cc + 2], hv.z, c2);
            c3 = fmaf(w3b[4 * cc + 3], hv.w, c3);
        }
        float v0 = fmaxf(b3r0 + ((a0 + a1) + (a2 + a3)), 0.0f);
        float v1 = fmaxf(b3r1 + ((c0 + c1) + (c2 + c3)), 0.0f);
        m0 = fmaxf(m0, v0);
        m1 = fmaxf(m1, v1);
    }
    out[(size_t)b * 128 * NPOINT + (size_t)lane        * NPOINT + p] = m0;
    out[(size_t)b * 128 * NPOINT + (size_t)(lane + 64) * NPOINT + p] = m1;
}

extern "C" void kernel_launch(void* const* d_in, const int* in_sizes, int n_in,
                              void* d_out, int out_size, void* d_ws, size_t ws_size,
                              hipStream_t stream) {
    const float* xyz  = (const float*)d_in[0];
    const float* feat = (const float*)d_in[1];
    const float* W1   = (const float*)d_in[2];
    const float* b1   = (const float*)d_in[3];
    const float* W2   = (const float*)d_in[4];
    const float* b2   = (const float*)d_in[5];
    const float* W3   = (const float*)d_in[6];
    const float* b3   = (const float*)d_in[7];
    float* out = (float*)d_out;

    float* out_newxyz = out;
    float* out_feat   = out + 4 * NPOINT * 3;

    fps_kernel<<<4, FPS_T, 0, stream>>>(xyz, out_newxyz);
    bq_mlp_kernel<<<1024, 256, 0, stream>>>(xyz, feat, W1, b1, W2, b2, W3, b3,
                                            out_newxyz, out_feat);
}